// Round 4
// baseline (253.040 us; speedup 1.0000x reference)
//
#include <hip/hip_runtime.h>

#define DD 64
#define BSH 8            // bucket = dst >> 8 (256 dsts per bucket)
#define NB_MAX 512       // supports n <= 131072
#define SCAP 4096        // staging slots per bucket (mean 3196, +16 sigma)
#define BIN_CH 4096      // edges per bin-kernel block

typedef __attribute__((ext_vector_type(8))) short bf16x8;
typedef __attribute__((ext_vector_type(4))) float f32x4;
union Frag { bf16x8 v; uint32_t d[4]; };

__device__ __forceinline__ float bf_lo(uint32_t d) { return __uint_as_float(d << 16); }
__device__ __forceinline__ float bf_hi(uint32_t d) { return __uint_as_float(d & 0xffff0000u); }
__device__ __forceinline__ float bf2f(uint32_t h) { return __uint_as_float(h << 16); }
__device__ __forceinline__ uint32_t f2bf(float f) {  // round-to-nearest-even
    uint32_t u = __float_as_uint(f);
    u += 0x7fffu + ((u >> 16) & 1u);
    return u >> 16;
}

// ====== K1: bin edges into dst-buckets (fixed-stride staging, LDS-aggregated) ======
__global__ __launch_bounds__(256) void bin_kernel(const int* __restrict__ src,
                                                  const int* __restrict__ dst,
                                                  int* __restrict__ bcnt,
                                                  uint32_t* __restrict__ staging,
                                                  int E, int NB) {
    __shared__ uint32_t cnt[NB_MAX];
    __shared__ uint32_t resv[NB_MAX];
    __shared__ uint16_t rk[BIN_CH];
    int tid = threadIdx.x;
    int base = blockIdx.x * BIN_CH;
    for (int b = tid; b < NB; b += 256) cnt[b] = 0;
    __syncthreads();
    for (int k = tid; k < BIN_CH; k += 256) {
        int g = base + k;
        if (g < E) {
            int b = dst[g] >> BSH;
            rk[k] = (uint16_t)atomicAdd(&cnt[b], 1u);
        }
    }
    __syncthreads();
    for (int b = tid; b < NB; b += 256) {
        uint32_t c = cnt[b];
        resv[b] = c ? (uint32_t)atomicAdd(&bcnt[b], (int)c) : 0u;
    }
    __syncthreads();
    for (int k = tid; k < BIN_CH; k += 256) {
        int g = base + k;
        if (g < E) {
            int s = src[g], d = dst[g];
            int b = d >> BSH;
            uint32_t pos = resv[b] + rk[k];
            if (pos < SCAP)  // statistically impossible overflow guard
                staging[(size_t)b * SCAP + pos] = ((uint32_t)s << BSH) | (uint32_t)(d & ((1 << BSH) - 1));
        }
    }
}

// ====== K3: per-bucket sort -> rowptr, inv, CSR srcs (coalesced out) ======
// srcs output is PRE-SHIFTED by 5 (dword offset of the 32-dword row).
__global__ __launch_bounds__(256) void sort_kernel(const int* __restrict__ bcnt,
                                                   const uint32_t* __restrict__ staging,
                                                   int* __restrict__ rowptr,
                                                   float* __restrict__ inv,
                                                   uint32_t* __restrict__ srcs,
                                                   int n, int E, int NB) {
    __shared__ uint32_t raw[SCAP];
    __shared__ uint32_t sorted[SCAP];
    __shared__ int scnt[1 << BSH];
    __shared__ int soff[1 << BSH];
    __shared__ int lcur[1 << BSH];
    __shared__ int red[256];
    int tid = threadIdx.x;
    int b = blockIdx.x;
    int base = b << BSH;
    int nd = min(1 << BSH, n - base);
    int cb = min(bcnt[b], SCAP);

    // bucket global base = prefix sum of bcnt[0..b)
    int part = 0;
    for (int j = tid; j < b; j += 256) part += bcnt[j];
    red[tid] = part;
    __syncthreads();
    for (int o = 128; o > 0; o >>= 1) {
        if (tid < o) red[tid] += red[tid + o];
        __syncthreads();
    }
    int bbase = red[0];

    // load records, histogram by local dst
    scnt[tid] = 0;
    __syncthreads();
    for (int k = tid; k < cb; k += 256) {
        uint32_t w = staging[(size_t)b * SCAP + k];
        raw[k] = w;
        atomicAdd(&scnt[w & ((1 << BSH) - 1)], 1);
    }
    __syncthreads();
    // exclusive scan of 256 counters (Hillis-Steele)
    int v = scnt[tid];
    red[tid] = v;
    __syncthreads();
    for (int o = 1; o < 256; o <<= 1) {
        int t = (tid >= o) ? red[tid - o] : 0;
        __syncthreads();
        red[tid] += t;
        __syncthreads();
    }
    soff[tid] = red[tid] - v;
    lcur[tid] = red[tid] - v;
    if (tid < nd) {
        rowptr[base + tid] = bbase + soff[tid];
        inv[base + tid] = rsqrtf((float)v + 1.0f);
    }
    if (b == NB - 1 && tid == 0) rowptr[n] = E;
    __syncthreads();
    // place into sorted order
    for (int k = tid; k < cb; k += 256) {
        uint32_t w = raw[k];
        int p = atomicAdd(&lcur[w & ((1 << BSH) - 1)], 1);
        sorted[p] = w >> BSH;
    }
    __syncthreads();
    for (int k = tid; k < cb; k += 256) srcs[bbase + k] = sorted[k] << 5;  // coalesced, pre-shifted
}

// ====== W-fragment setup: precompute per-lane split-bf16 MFMA B-fragments ======
// One block, 128 threads: half=tid>>6 selects {W1,W2}. Layout per lane:
//   Wf[(half*64+lane)*64 + t*8 + c*4 + i]      = hi dword (i consecutive -> int4 load)
//   Wf[(half*64+lane)*64 + 32 + t*8 + c*4 + i] = lo dword
__global__ __launch_bounds__(128) void wsetup_kernel(const float* __restrict__ W1,
                                                     const float* __restrict__ W2,
                                                     uint32_t* __restrict__ Wf) {
    int tid = threadIdx.x;
    int half = tid >> 6, lane = tid & 63;
    const float* W = half ? W2 : W1;
    int quad = lane >> 4, l16 = lane & 15;
    uint32_t* out = Wf + (size_t)(half * 64 + lane) * 64;
#pragma unroll
    for (int t = 0; t < 4; ++t)
#pragma unroll
        for (int c = 0; c < 2; ++c) {
            int col = t * 16 + l16;
            int kb = c * 32 + quad * 8;
#pragma unroll
            for (int i = 0; i < 4; ++i) {
                float w0 = W[(kb + 2 * i) * DD + col];
                float w1 = W[(kb + 2 * i + 1) * DD + col];
                uint32_t h0 = f2bf(w0), h1 = f2bf(w1);
                uint32_t l0 = f2bf(w0 - bf2f(h0)), l1 = f2bf(w1 - bf2f(h1));
                out[t * 8 + c * 4 + i] = h0 | (h1 << 16);
                out[32 + t * 8 + c * 4 + i] = l0 | (l1 << 16);
            }
        }
}

// ====== MFMA GEMM: [n,64] @ [64,64] -> bf16 rows PRE-SCALED by inv[row]. ======
// 16x16x32 bf16, split-bf16 = fp32-exact. B-fragments preloaded from Wf (L2-hot,
// 16x dwordx4) -- no LDS staging, no per-wave split VALU, no __syncthreads.
template <int XBF>
__global__ __launch_bounds__(256) void gemm64_mfma(const void* __restrict__ Xv,
                                                   const uint32_t* __restrict__ Wf,
                                                   const float* __restrict__ inv,
                                                   uint16_t* __restrict__ Y, int n, int wsel) {
    int tid = threadIdx.x;
    int lane = tid & 63, quad = lane >> 4, l16 = lane & 15;

    const uint32_t* fb = Wf + (size_t)(wsel * 64 + lane) * 64;
    Frag bhi[4][2], blo[4][2];
#pragma unroll
    for (int t = 0; t < 4; ++t)
#pragma unroll
        for (int c = 0; c < 2; ++c) {
            int4 hv = *(const int4*)(fb + t * 8 + c * 4);
            int4 lv = *(const int4*)(fb + 32 + t * 8 + c * 4);
            bhi[t][c].d[0] = hv.x; bhi[t][c].d[1] = hv.y; bhi[t][c].d[2] = hv.z; bhi[t][c].d[3] = hv.w;
            blo[t][c].d[0] = lv.x; blo[t][c].d[1] = lv.y; blo[t][c].d[2] = lv.z; blo[t][c].d[3] = lv.w;
        }

    int ngroups = (n + 15) >> 4;
    int nwaves = gridDim.x * 4;
    int wid = blockIdx.x * 4 + (tid >> 6);
    for (int g = wid; g < ngroups; g += nwaves) {
        int rb = g << 4;
        int row = min(rb + l16, n - 1);
        f32x4 acc[4];
#pragma unroll
        for (int t = 0; t < 4; ++t) acc[t] = (f32x4){0.f, 0.f, 0.f, 0.f};
#pragma unroll
        for (int c = 0; c < 2; ++c) {
            Frag ahi, alo;
            if constexpr (XBF == 0) {
                const float* xr = (const float*)Xv + (size_t)row * DD + c * 32 + quad * 8;
                float4 x0 = *(const float4*)xr;
                float4 x1 = *(const float4*)(xr + 4);
                float f[8] = {x0.x, x0.y, x0.z, x0.w, x1.x, x1.y, x1.z, x1.w};
#pragma unroll
                for (int i = 0; i < 4; ++i) {
                    uint32_t h0 = f2bf(f[2 * i]), h1 = f2bf(f[2 * i + 1]);
                    ahi.d[i] = h0 | (h1 << 16);
                    alo.d[i] = f2bf(f[2 * i] - bf2f(h0)) | (f2bf(f[2 * i + 1] - bf2f(h1)) << 16);
                }
            } else {
                const int4* xr = (const int4*)((const uint32_t*)Xv + (size_t)row * 32 + c * 16 + quad * 4);
                int4 a = *xr;
                ahi.d[0] = a.x; ahi.d[1] = a.y; ahi.d[2] = a.z; ahi.d[3] = a.w;
            }
#pragma unroll
            for (int t = 0; t < 4; ++t) {
                acc[t] = __builtin_amdgcn_mfma_f32_16x16x32_bf16(ahi.v, bhi[t][c].v, acc[t], 0, 0, 0);
                acc[t] = __builtin_amdgcn_mfma_f32_16x16x32_bf16(ahi.v, blo[t][c].v, acc[t], 0, 0, 0);
                if constexpr (XBF == 0)
                    acc[t] = __builtin_amdgcn_mfma_f32_16x16x32_bf16(alo.v, bhi[t][c].v, acc[t], 0, 0, 0);
            }
        }
#pragma unroll
        for (int r = 0; r < 4; ++r) {
            int ro = rb + quad * 4 + r;
            if (ro < n) {
                float sc = inv[ro];
#pragma unroll
                for (int t = 0; t < 4; ++t)
                    Y[(size_t)ro * DD + t * 16 + l16] = (uint16_t)f2bf(acc[t][r] * sc);
            }
        }
    }
}

// ====== fused aggregation: TWO nodes per wave (32 lanes each), 4 edge-streams/node ======
// Half h (lanes h*32..h*32+31) owns node 2w+h. Group g (8 lanes) owns edge stream
// jstart+g, +4, ...; lane m loads row dwords 4m..4m+3 (16 B). Rows pre-scaled by
// inv[src]; whole sum (incl. self row) scaled by inv[dst] once at the end.
// Deep pipeline: 5 rows + 6 srcs in flight per stream (40 rows/wave). Avg trips
// ~3.1 -> ~98% of nodes fully issue from the branch-free prologue.
template <int MODE>
__global__ __launch_bounds__(256) void agg_kernel(const int* __restrict__ rowptr,
                                                  const uint32_t* __restrict__ srcs,  // pre-shifted <<5
                                                  const float* __restrict__ inv,
                                                  const uint32_t* __restrict__ XWb,  // [n][32] dwords
                                                  const float* __restrict__ b,
                                                  void* __restrict__ OUTv, int n) {
    int gid = blockIdx.x * 256 + threadIdx.x;
    int w = gid >> 6, lane = gid & 63;
    if (w * 2 >= n) return;
    int h = lane >> 5, l = lane & 31;
    int i = w * 2 + h;
    bool act = i < n;
    int ic = act ? i : n - 1;
    int g = l >> 3, m = l & 7;

    float a[8];
#pragma unroll
    for (int k = 0; k < 8; ++k) a[k] = 0.f;
    if (g == 0) {  // self-loop: row ic is pre-scaled by inv[ic]; final *iv gives inv^2
        int4 d = *(const int4*)(XWb + (size_t)ic * 32 + 4 * m);
        a[0] = bf_lo((uint32_t)d.x); a[1] = bf_hi((uint32_t)d.x);
        a[2] = bf_lo((uint32_t)d.y); a[3] = bf_hi((uint32_t)d.y);
        a[4] = bf_lo((uint32_t)d.z); a[5] = bf_hi((uint32_t)d.z);
        a[6] = bf_lo((uint32_t)d.w); a[7] = bf_hi((uint32_t)d.w);
    }

    int jstart = rowptr[ic];
    int jend = act ? rowptr[ic + 1] : jstart;
    if (jstart < jend) {
        int last = jend - 1;
        int jq = jstart + g;  // this group's stream: jq, jq+4, ...
        // prologue: 6 srcs + 5 rows in flight
        uint32_t s0 = srcs[min(jq, last)];
        uint32_t s1 = srcs[min(jq + 4, last)];
        uint32_t s2 = srcs[min(jq + 8, last)];
        uint32_t s3 = srcs[min(jq + 12, last)];
        uint32_t s4 = srcs[min(jq + 16, last)];
        uint32_t sp = srcs[min(jq + 20, last)];
        int4 d0 = *(const int4*)(XWb + s0 + 4 * m);
        int4 d1 = *(const int4*)(XWb + s1 + 4 * m);
        int4 d2 = *(const int4*)(XWb + s2 + 4 * m);
        int4 d3 = *(const int4*)(XWb + s3 + 4 * m);
        int4 d4 = *(const int4*)(XWb + s4 + 4 * m);
        for (int j = jq; j < jend; j += 4) {
            uint32_t snext = srcs[min(j + 24, last)];     // src prefetch (6 ahead)
            int4 dnew = *(const int4*)(XWb + sp + 4 * m); // row prefetch (5 ahead)
            a[0] += bf_lo((uint32_t)d0.x); a[1] += bf_hi((uint32_t)d0.x);
            a[2] += bf_lo((uint32_t)d0.y); a[3] += bf_hi((uint32_t)d0.y);
            a[4] += bf_lo((uint32_t)d0.z); a[5] += bf_hi((uint32_t)d0.z);
            a[6] += bf_lo((uint32_t)d0.w); a[7] += bf_hi((uint32_t)d0.w);
            d0 = d1; d1 = d2; d2 = d3; d3 = d4; d4 = dnew;
            sp = snext;
        }
    }

    // combine 4 groups within each half: lanes {l^8, l^16} (all intra-half)
#pragma unroll
    for (int k = 0; k < 8; ++k) {
        a[k] += __shfl_xor(a[k], 8, 64);
        a[k] += __shfl_xor(a[k], 16, 64);
    }

    float iv = inv[ic];  // half-uniform
    float4 bb0 = *(const float4*)(b + 8 * m);
    float4 bb1 = *(const float4*)(b + 8 * m + 4);
    float f0 = fmaf(a[0], iv, bb0.x), f1 = fmaf(a[1], iv, bb0.y);
    float f2 = fmaf(a[2], iv, bb0.z), f3 = fmaf(a[3], iv, bb0.w);
    float f4 = fmaf(a[4], iv, bb1.x), f5 = fmaf(a[5], iv, bb1.y);
    float f6 = fmaf(a[6], iv, bb1.z), f7 = fmaf(a[7], iv, bb1.w);

    if (MODE == 0) {
        if (act && g == 0) {
            int4 d;
            d.x = (int)((f2bf(fmaxf(f1, 0.f)) << 16) | f2bf(fmaxf(f0, 0.f)));
            d.y = (int)((f2bf(fmaxf(f3, 0.f)) << 16) | f2bf(fmaxf(f2, 0.f)));
            d.z = (int)((f2bf(fmaxf(f5, 0.f)) << 16) | f2bf(fmaxf(f4, 0.f)));
            d.w = (int)((f2bf(fmaxf(f7, 0.f)) << 16) | f2bf(fmaxf(f6, 0.f)));
            *(int4*)((uint32_t*)OUTv + (size_t)i * 32 + 4 * m) = d;
        }
    } else {
        // cross-feature reduce over m (lanes l^4, l^2, l^1 — intra-half)
        float mx = fmaxf(fmaxf(fmaxf(f0, f1), fmaxf(f2, f3)),
                         fmaxf(fmaxf(f4, f5), fmaxf(f6, f7)));
#pragma unroll
        for (int o = 4; o > 0; o >>= 1) mx = fmaxf(mx, __shfl_xor(mx, o, 64));
        float e = __expf(f0 - mx) + __expf(f1 - mx) + __expf(f2 - mx) + __expf(f3 - mx)
                + __expf(f4 - mx) + __expf(f5 - mx) + __expf(f6 - mx) + __expf(f7 - mx);
#pragma unroll
        for (int o = 4; o > 0; o >>= 1) e += __shfl_xor(e, o, 64);
        float ls = __logf(e);
        if (act && g == 0) {
            float4 r0 = make_float4(f0 - mx - ls, f1 - mx - ls, f2 - mx - ls, f3 - mx - ls);
            float4 r1 = make_float4(f4 - mx - ls, f5 - mx - ls, f6 - mx - ls, f7 - mx - ls);
            *(float4*)((float*)OUTv + (size_t)i * DD + 8 * m) = r0;
            *(float4*)((float*)OUTv + (size_t)i * DD + 8 * m + 4) = r1;
        }
    }
}

extern "C" void kernel_launch(void* const* d_in, const int* in_sizes, int n_in,
                              void* d_out, int out_size, void* d_ws, size_t ws_size,
                              hipStream_t stream) {
    const float* x  = (const float*)d_in[0];
    const int*   ei = (const int*)d_in[1];
    const float* W1 = (const float*)d_in[2];
    const float* b1 = (const float*)d_in[3];
    const float* W2 = (const float*)d_in[4];
    const float* b2 = (const float*)d_in[5];
    float* out = (float*)d_out;

    const int n = in_sizes[0] / DD;
    const int E = in_sizes[1] / 2;
    const int* src = ei;
    const int* dst = ei + E;
    const int NB = (n + (1 << BSH) - 1) >> BSH;  // 391 for n=100k

    // workspace layout (int units)
    size_t off = 0;
    int* base = (int*)d_ws;
    int* bcnt = base + off; off += NB_MAX;
    uint32_t* staging = (uint32_t*)(base + off); off += (size_t)NB_MAX * SCAP;
    uint32_t* srcs = (uint32_t*)(base + off); off += E;
    int* rowptr = base + off; off += (size_t)n + 1;
    float* inv  = (float*)(base + off); off += n;
    uint32_t* XWb = (uint32_t*)(base + off); off += (size_t)n * 32;  // bf16 [n][64]
    uint32_t* hb  = (uint32_t*)(base + off); off += (size_t)n * 32;  // bf16 [n][64]
    uint32_t* Wf  = (uint32_t*)(base + off); off += 128 * 64;        // W fragments (32 KB)

    hipMemsetAsync(bcnt, 0, NB_MAX * sizeof(int), stream);
    wsetup_kernel<<<1, 128, 0, stream>>>(W1, W2, Wf);
    bin_kernel<<<(E + BIN_CH - 1) / BIN_CH, 256, 0, stream>>>(src, dst, bcnt, staging, E, NB);
    sort_kernel<<<NB, 256, 0, stream>>>(bcnt, staging, rowptr, inv, srcs, n, E, NB);

    // gemm grid: exactly one 16-row group per wave (setup is now ~free)
    const int ngroups = (n + 15) >> 4;
    const int gblocks = (ngroups + 3) / 4;
    // agg grid: two nodes per wave (4 waves/block)
    const int ablocks = (n + 7) / 8;

    // layer 1 (gemm pre-scales rows by inv[row]; needs sort_kernel's inv -> same stream, ordered)
    gemm64_mfma<0><<<gblocks, 256, 0, stream>>>(x, Wf, inv, (uint16_t*)XWb, n, 0);
    agg_kernel<0><<<ablocks, 256, 0, stream>>>(rowptr, srcs, inv, XWb, b1, hb, n);

    // layer 2
    gemm64_mfma<1><<<gblocks, 256, 0, stream>>>(hb, Wf, inv, (uint16_t*)XWb, n, 1);
    agg_kernel<1><<<ablocks, 256, 0, stream>>>(rowptr, srcs, inv, XWb, b2, out, n);
}

// Round 9
// 237.292 us; speedup vs baseline: 1.0664x; 1.0664x over previous
//
#include <hip/hip_runtime.h>

#define DD 64
#define BSH 8            // bucket = dst >> 8 (256 dsts per bucket)
#define NB_MAX 512       // supports n <= 131072
#define SCAP 4096        // staging slots per bucket (mean 3196, +16 sigma)
#define BIN_CH 4096      // edges per bin-kernel block

typedef __attribute__((ext_vector_type(8))) short bf16x8;
typedef __attribute__((ext_vector_type(4))) float f32x4;
union Frag { bf16x8 v; uint32_t d[4]; };

__device__ __forceinline__ float bf_lo(uint32_t d) { return __uint_as_float(d << 16); }
__device__ __forceinline__ float bf_hi(uint32_t d) { return __uint_as_float(d & 0xffff0000u); }
__device__ __forceinline__ float bf2f(uint32_t h) { return __uint_as_float(h << 16); }
__device__ __forceinline__ uint32_t f2bf(float f) {  // round-to-nearest-even
    uint32_t u = __float_as_uint(f);
    u += 0x7fffu + ((u >> 16) & 1u);
    return u >> 16;
}

// ====== K1: bin edges into dst-buckets (fixed-stride staging, LDS-aggregated) ======
__global__ __launch_bounds__(256) void bin_kernel(const int* __restrict__ src,
                                                  const int* __restrict__ dst,
                                                  int* __restrict__ bcnt,
                                                  uint32_t* __restrict__ staging,
                                                  int E, int NB) {
    __shared__ uint32_t cnt[NB_MAX];
    __shared__ uint32_t resv[NB_MAX];
    __shared__ uint16_t rk[BIN_CH];
    int tid = threadIdx.x;
    int base = blockIdx.x * BIN_CH;
    for (int b = tid; b < NB; b += 256) cnt[b] = 0;
    __syncthreads();
    for (int k = tid; k < BIN_CH; k += 256) {
        int g = base + k;
        if (g < E) {
            int b = dst[g] >> BSH;
            rk[k] = (uint16_t)atomicAdd(&cnt[b], 1u);
        }
    }
    __syncthreads();
    for (int b = tid; b < NB; b += 256) {
        uint32_t c = cnt[b];
        resv[b] = c ? (uint32_t)atomicAdd(&bcnt[b], (int)c) : 0u;
    }
    __syncthreads();
    for (int k = tid; k < BIN_CH; k += 256) {
        int g = base + k;
        if (g < E) {
            int s = src[g], d = dst[g];
            int b = d >> BSH;
            uint32_t pos = resv[b] + rk[k];
            if (pos < SCAP)  // statistically impossible overflow guard
                staging[(size_t)b * SCAP + pos] = ((uint32_t)s << BSH) | (uint32_t)(d & ((1 << BSH) - 1));
        }
    }
}

// ====== K3: per-bucket sort -> rowptr, inv, CSR srcs (coalesced out) ======
// srcs output is PRE-SHIFTED by 5 (dword offset of the 32-dword row).
// Wave-level shfl scans: 3 __syncthreads total on the scan paths (was ~24).
__global__ __launch_bounds__(256) void sort_kernel(const int* __restrict__ bcnt,
                                                   const uint32_t* __restrict__ staging,
                                                   int* __restrict__ rowptr,
                                                   float* __restrict__ inv,
                                                   uint32_t* __restrict__ srcs,
                                                   int n, int E, int NB) {
    __shared__ uint32_t raw[SCAP];
    __shared__ uint32_t sorted[SCAP];
    __shared__ int scnt[1 << BSH];
    __shared__ int soff[1 << BSH];
    __shared__ int lcur[1 << BSH];
    __shared__ int wred[4];
    __shared__ int wsum[4];
    int tid = threadIdx.x;
    int lane = tid & 63, wv = tid >> 6;
    int b = blockIdx.x;
    int base = b << BSH;
    int nd = min(1 << BSH, n - base);
    int cb = min(bcnt[b], SCAP);

    // bucket global base = prefix sum of bcnt[0..b): per-thread partials,
    // wave shfl-reduce (no barriers), cross-wave via LDS (1 barrier).
    int part = 0;
    for (int j = tid; j < b; j += 256) part += bcnt[j];
#pragma unroll
    for (int o = 1; o < 64; o <<= 1) part += __shfl_xor(part, o, 64);
    if (lane == 0) wred[wv] = part;
    // zero histogram before the same barrier
    scnt[tid] = 0;
    __syncthreads();
    int bbase = wred[0] + wred[1] + wred[2] + wred[3];

    // load records, histogram by local dst
    for (int k = tid; k < cb; k += 256) {
        uint32_t w = staging[(size_t)b * SCAP + k];
        raw[k] = w;
        atomicAdd(&scnt[w & ((1 << BSH) - 1)], 1);
    }
    __syncthreads();
    // exclusive scan of 256 counters: wave shfl inclusive scan + cross-wave offsets
    int v = scnt[tid];
    int sc = v;
#pragma unroll
    for (int o = 1; o < 64; o <<= 1) {
        int t = __shfl_up(sc, o, 64);
        if (lane >= o) sc += t;
    }
    if (lane == 63) wsum[wv] = sc;
    __syncthreads();
    int add = 0;
    if (wv > 0) add += wsum[0];
    if (wv > 1) add += wsum[1];
    if (wv > 2) add += wsum[2];
    int incl = sc + add;
    soff[tid] = incl - v;
    lcur[tid] = incl - v;
    if (tid < nd) {
        rowptr[base + tid] = bbase + soff[tid];
        inv[base + tid] = rsqrtf((float)v + 1.0f);
    }
    if (b == NB - 1 && tid == 0) rowptr[n] = E;
    __syncthreads();
    // place into sorted order
    for (int k = tid; k < cb; k += 256) {
        uint32_t w = raw[k];
        int p = atomicAdd(&lcur[w & ((1 << BSH) - 1)], 1);
        sorted[p] = w >> BSH;
    }
    __syncthreads();
    for (int k = tid; k < cb; k += 256) srcs[bbase + k] = sorted[k] << 5;  // coalesced, pre-shifted
}

// ====== MFMA GEMM: [n,64] @ [64,64] -> bf16 rows PRE-SCALED by inv[row]. ======
// R2-measured config: LDS-staged W, per-wave fragment build, 1024-block grid.
// 16x16x32 bf16, split-bf16 = fp32-exact.
template <int XBF>
__global__ __launch_bounds__(256) void gemm64_mfma(const void* __restrict__ Xv,
                                                   const float* __restrict__ W,
                                                   const float* __restrict__ inv,
                                                   uint16_t* __restrict__ Y, int n) {
    __shared__ float Ws[DD * DD];
    int tid = threadIdx.x;
    for (int i = tid; i < DD * DD; i += 256) Ws[i] = W[i];
    __syncthreads();
    int lane = tid & 63, quad = lane >> 4, l16 = lane & 15;

    Frag bhi[4][2], blo[4][2];
#pragma unroll
    for (int t = 0; t < 4; ++t)
#pragma unroll
        for (int c = 0; c < 2; ++c) {
            int col = t * 16 + l16;
            int kb = c * 32 + quad * 8;
#pragma unroll
            for (int i = 0; i < 4; ++i) {
                float w0 = Ws[(kb + 2 * i) * DD + col];
                float w1 = Ws[(kb + 2 * i + 1) * DD + col];
                uint32_t h0 = f2bf(w0), h1 = f2bf(w1);
                uint32_t l0 = f2bf(w0 - bf2f(h0)), l1 = f2bf(w1 - bf2f(h1));
                bhi[t][c].d[i] = h0 | (h1 << 16);
                blo[t][c].d[i] = l0 | (l1 << 16);
            }
        }

    int ngroups = (n + 15) >> 4;
    int nwaves = gridDim.x * 4;
    int wid = blockIdx.x * 4 + (tid >> 6);
    for (int g = wid; g < ngroups; g += nwaves) {
        int rb = g << 4;
        int row = min(rb + l16, n - 1);
        f32x4 acc[4];
#pragma unroll
        for (int t = 0; t < 4; ++t) acc[t] = (f32x4){0.f, 0.f, 0.f, 0.f};
#pragma unroll
        for (int c = 0; c < 2; ++c) {
            Frag ahi, alo;
            if constexpr (XBF == 0) {
                const float* xr = (const float*)Xv + (size_t)row * DD + c * 32 + quad * 8;
                float4 x0 = *(const float4*)xr;
                float4 x1 = *(const float4*)(xr + 4);
                float f[8] = {x0.x, x0.y, x0.z, x0.w, x1.x, x1.y, x1.z, x1.w};
#pragma unroll
                for (int i = 0; i < 4; ++i) {
                    uint32_t h0 = f2bf(f[2 * i]), h1 = f2bf(f[2 * i + 1]);
                    ahi.d[i] = h0 | (h1 << 16);
                    alo.d[i] = f2bf(f[2 * i] - bf2f(h0)) | (f2bf(f[2 * i + 1] - bf2f(h1)) << 16);
                }
            } else {
                const int4* xr = (const int4*)((const uint32_t*)Xv + (size_t)row * 32 + c * 16 + quad * 4);
                int4 a = *xr;
                ahi.d[0] = a.x; ahi.d[1] = a.y; ahi.d[2] = a.z; ahi.d[3] = a.w;
            }
#pragma unroll
            for (int t = 0; t < 4; ++t) {
                acc[t] = __builtin_amdgcn_mfma_f32_16x16x32_bf16(ahi.v, bhi[t][c].v, acc[t], 0, 0, 0);
                acc[t] = __builtin_amdgcn_mfma_f32_16x16x32_bf16(ahi.v, blo[t][c].v, acc[t], 0, 0, 0);
                if constexpr (XBF == 0)
                    acc[t] = __builtin_amdgcn_mfma_f32_16x16x32_bf16(alo.v, bhi[t][c].v, acc[t], 0, 0, 0);
            }
        }
#pragma unroll
        for (int r = 0; r < 4; ++r) {
            int ro = rb + quad * 4 + r;
            if (ro < n) {
                float sc = inv[ro];
#pragma unroll
                for (int t = 0; t < 4; ++t)
                    Y[(size_t)ro * DD + t * 16 + l16] = (uint16_t)f2bf(acc[t][r] * sc);
            }
        }
    }
}

// ====== fused aggregation: TWO nodes per wave (32 lanes each), 4 edge-streams/node ======
// R3-measured config (best: 48.0 us, VGPR 16): 3 rows + 4 srcs in flight per stream.
// Half h (lanes h*32..h*32+31) owns node 2w+h. Group g (8 lanes) owns edge stream
// jstart+g, +4, ...; lane m loads row dwords 4m..4m+3 (16 B). Rows pre-scaled by
// inv[src]; whole sum (incl. self row) scaled by inv[dst] once at the end.
template <int MODE>
__global__ __launch_bounds__(256) void agg_kernel(const int* __restrict__ rowptr,
                                                  const uint32_t* __restrict__ srcs,  // pre-shifted <<5
                                                  const float* __restrict__ inv,
                                                  const uint32_t* __restrict__ XWb,  // [n][32] dwords
                                                  const float* __restrict__ b,
                                                  void* __restrict__ OUTv, int n) {
    int gid = blockIdx.x * 256 + threadIdx.x;
    int w = gid >> 6, lane = gid & 63;
    if (w * 2 >= n) return;
    int h = lane >> 5, l = lane & 31;
    int i = w * 2 + h;
    bool act = i < n;
    int ic = act ? i : n - 1;
    int g = l >> 3, m = l & 7;

    float a[8];
#pragma unroll
    for (int k = 0; k < 8; ++k) a[k] = 0.f;
    if (g == 0) {  // self-loop: row ic is pre-scaled by inv[ic]; final *iv gives inv^2
        int4 d = *(const int4*)(XWb + (size_t)ic * 32 + 4 * m);
        a[0] = bf_lo((uint32_t)d.x); a[1] = bf_hi((uint32_t)d.x);
        a[2] = bf_lo((uint32_t)d.y); a[3] = bf_hi((uint32_t)d.y);
        a[4] = bf_lo((uint32_t)d.z); a[5] = bf_hi((uint32_t)d.z);
        a[6] = bf_lo((uint32_t)d.w); a[7] = bf_hi((uint32_t)d.w);
    }

    int jstart = rowptr[ic];
    int jend = act ? rowptr[ic + 1] : jstart;
    if (jstart < jend) {
        int last = jend - 1;
        int jq = jstart + g;  // this group's stream: jq, jq+4, ...
        uint32_t s0 = srcs[min(jq, last)];
        uint32_t s1 = srcs[min(jq + 4, last)];
        uint32_t s2 = srcs[min(jq + 8, last)];
        uint32_t s3 = srcs[min(jq + 12, last)];
        int4 d0 = *(const int4*)(XWb + s0 + 4 * m);
        int4 d1 = *(const int4*)(XWb + s1 + 4 * m);
        int4 d2 = *(const int4*)(XWb + s2 + 4 * m);
        for (int j = jq; j < jend; j += 4) {
            uint32_t s4 = srcs[min(j + 16, last)];            // src prefetch (4 ahead)
            int4 d3 = *(const int4*)(XWb + s3 + 4 * m);       // row prefetch (3 ahead)
            a[0] += bf_lo((uint32_t)d0.x); a[1] += bf_hi((uint32_t)d0.x);
            a[2] += bf_lo((uint32_t)d0.y); a[3] += bf_hi((uint32_t)d0.y);
            a[4] += bf_lo((uint32_t)d0.z); a[5] += bf_hi((uint32_t)d0.z);
            a[6] += bf_lo((uint32_t)d0.w); a[7] += bf_hi((uint32_t)d0.w);
            s3 = s4;
            d0 = d1; d1 = d2; d2 = d3;
        }
    }

    // combine 4 groups within each half: lanes {l^8, l^16} (all intra-half)
#pragma unroll
    for (int k = 0; k < 8; ++k) {
        a[k] += __shfl_xor(a[k], 8, 64);
        a[k] += __shfl_xor(a[k], 16, 64);
    }

    float iv = inv[ic];  // half-uniform
    float4 bb0 = *(const float4*)(b + 8 * m);
    float4 bb1 = *(const float4*)(b + 8 * m + 4);
    float f0 = fmaf(a[0], iv, bb0.x), f1 = fmaf(a[1], iv, bb0.y);
    float f2 = fmaf(a[2], iv, bb0.z), f3 = fmaf(a[3], iv, bb0.w);
    float f4 = fmaf(a[4], iv, bb1.x), f5 = fmaf(a[5], iv, bb1.y);
    float f6 = fmaf(a[6], iv, bb1.z), f7 = fmaf(a[7], iv, bb1.w);

    if (MODE == 0) {
        if (act && g == 0) {
            int4 d;
            d.x = (int)((f2bf(fmaxf(f1, 0.f)) << 16) | f2bf(fmaxf(f0, 0.f)));
            d.y = (int)((f2bf(fmaxf(f3, 0.f)) << 16) | f2bf(fmaxf(f2, 0.f)));
            d.z = (int)((f2bf(fmaxf(f5, 0.f)) << 16) | f2bf(fmaxf(f4, 0.f)));
            d.w = (int)((f2bf(fmaxf(f7, 0.f)) << 16) | f2bf(fmaxf(f6, 0.f)));
            *(int4*)((uint32_t*)OUTv + (size_t)i * 32 + 4 * m) = d;
        }
    } else {
        // cross-feature reduce over m (lanes l^4, l^2, l^1 — intra-half)
        float mx = fmaxf(fmaxf(fmaxf(f0, f1), fmaxf(f2, f3)),
                         fmaxf(fmaxf(f4, f5), fmaxf(f6, f7)));
#pragma unroll
        for (int o = 4; o > 0; o >>= 1) mx = fmaxf(mx, __shfl_xor(mx, o, 64));
        float e = __expf(f0 - mx) + __expf(f1 - mx) + __expf(f2 - mx) + __expf(f3 - mx)
                + __expf(f4 - mx) + __expf(f5 - mx) + __expf(f6 - mx) + __expf(f7 - mx);
#pragma unroll
        for (int o = 4; o > 0; o >>= 1) e += __shfl_xor(e, o, 64);
        float ls = __logf(e);
        if (act && g == 0) {
            float4 r0 = make_float4(f0 - mx - ls, f1 - mx - ls, f2 - mx - ls, f3 - mx - ls);
            float4 r1 = make_float4(f4 - mx - ls, f5 - mx - ls, f6 - mx - ls, f7 - mx - ls);
            *(float4*)((float*)OUTv + (size_t)i * DD + 8 * m) = r0;
            *(float4*)((float*)OUTv + (size_t)i * DD + 8 * m + 4) = r1;
        }
    }
}

extern "C" void kernel_launch(void* const* d_in, const int* in_sizes, int n_in,
                              void* d_out, int out_size, void* d_ws, size_t ws_size,
                              hipStream_t stream) {
    const float* x  = (const float*)d_in[0];
    const int*   ei = (const int*)d_in[1];
    const float* W1 = (const float*)d_in[2];
    const float* b1 = (const float*)d_in[3];
    const float* W2 = (const float*)d_in[4];
    const float* b2 = (const float*)d_in[5];
    float* out = (float*)d_out;

    const int n = in_sizes[0] / DD;
    const int E = in_sizes[1] / 2;
    const int* src = ei;
    const int* dst = ei + E;
    const int NB = (n + (1 << BSH) - 1) >> BSH;  // 391 for n=100k

    // workspace layout (int units)
    size_t off = 0;
    int* base = (int*)d_ws;
    int* bcnt = base + off; off += NB_MAX;
    uint32_t* staging = (uint32_t*)(base + off); off += (size_t)NB_MAX * SCAP;
    uint32_t* srcs = (uint32_t*)(base + off); off += E;
    int* rowptr = base + off; off += (size_t)n + 1;
    float* inv  = (float*)(base + off); off += n;
    uint32_t* XWb = (uint32_t*)(base + off); off += (size_t)n * 32;  // bf16 [n][64]
    uint32_t* hb  = (uint32_t*)(base + off); off += (size_t)n * 32;  // bf16 [n][64]

    hipMemsetAsync(bcnt, 0, NB_MAX * sizeof(int), stream);
    bin_kernel<<<(E + BIN_CH - 1) / BIN_CH, 256, 0, stream>>>(src, dst, bcnt, staging, E, NB);
    sort_kernel<<<NB, 256, 0, stream>>>(bcnt, staging, rowptr, inv, srcs, n, E, NB);

    // agg grid: two nodes per wave (4 waves/block)
    const int ablocks = (n + 7) / 8;

    // layer 1 (gemm pre-scales rows by inv[row]; needs sort_kernel's inv -> same stream, ordered)
    gemm64_mfma<0><<<1024, 256, 0, stream>>>(x, W1, inv, (uint16_t*)XWb, n);
    agg_kernel<0><<<ablocks, 256, 0, stream>>>(rowptr, srcs, inv, XWb, b1, hb, n);

    // layer 2
    gemm64_mfma<1><<<1024, 256, 0, stream>>>(hb, W2, inv, (uint16_t*)XWb, n);
    agg_kernel<1><<<ablocks, 256, 0, stream>>>(rowptr, srcs, inv, XWb, b2, out, n);
}

// Round 10
// 230.603 us; speedup vs baseline: 1.0973x; 1.0290x over previous
//
#include <hip/hip_runtime.h>

#define DD 64
#define BSH 8            // bucket = dst >> 8 (256 dsts per bucket)
#define NB_MAX 512       // supports n <= 131072
#define SCAP 4096        // staging slots per bucket (mean 3196, +16 sigma)
#define BIN_CH 4096      // edges per bin-kernel block

typedef __attribute__((ext_vector_type(8))) short bf16x8;
typedef __attribute__((ext_vector_type(4))) float f32x4;
union Frag { bf16x8 v; uint32_t d[4]; };

__device__ __forceinline__ float bf_lo(uint32_t d) { return __uint_as_float(d << 16); }
__device__ __forceinline__ float bf_hi(uint32_t d) { return __uint_as_float(d & 0xffff0000u); }
__device__ __forceinline__ float bf2f(uint32_t h) { return __uint_as_float(h << 16); }
__device__ __forceinline__ uint32_t f2bf(float f) {  // round-to-nearest-even
    uint32_t u = __float_as_uint(f);
    u += 0x7fffu + ((u >> 16) & 1u);
    return u >> 16;
}

// ====== K1: bin edges into dst-buckets, in-LDS GROUPED staging writes ======
// v2: histogram -> 512-entry shfl scan -> LDS scatter by bucket -> per-bucket
// contiguous flush. Replaces 1.25M random 4B stores (16x line amplification,
// ~78 MB effective) with ~500 short coalesced runs per block (~2x, ~9 MB).
__global__ __launch_bounds__(256) void bin_kernel(const int* __restrict__ src,
                                                  const int* __restrict__ dst,
                                                  int* __restrict__ bcnt,
                                                  uint32_t* __restrict__ staging,
                                                  int E, int NB) {
    __shared__ uint32_t sorted[BIN_CH];   // records grouped by bucket
    __shared__ int cnt[NB_MAX];
    __shared__ int loc[NB_MAX];           // exclusive offset, bumped to end by scatter
    __shared__ int resv[NB_MAX];
    __shared__ int wsum[4][2];
    int tid = threadIdx.x;
    int lane = tid & 63, wv = tid >> 6;
    int base = blockIdx.x * BIN_CH;
    int cE = min(BIN_CH, E - base);

    cnt[tid] = 0; cnt[tid + 256] = 0;
    __syncthreads();
    // pass 1: histogram dst-buckets
    for (int k = tid; k < cE; k += 256)
        atomicAdd(&cnt[dst[base + k] >> BSH], 1);
    __syncthreads();
    // exclusive scan over 512 counters: thread t owns counters t and t+256
    int v0 = cnt[tid], v1 = cnt[tid + 256];
    int s0 = v0, s1 = v1;
#pragma unroll
    for (int o = 1; o < 64; o <<= 1) {
        int t0 = __shfl_up(s0, o, 64);
        int t1 = __shfl_up(s1, o, 64);
        if (lane >= o) { s0 += t0; s1 += t1; }
    }
    if (lane == 63) { wsum[wv][0] = s0; wsum[wv][1] = s1; }
    __syncthreads();
    int add0 = 0, add1 = 0;
    for (int w = 0; w < wv; ++w) { add0 += wsum[w][0]; add1 += wsum[w][1]; }
    int tot0 = wsum[0][0] + wsum[1][0] + wsum[2][0] + wsum[3][0];
    int e0 = s0 + add0 - v0;          // exclusive offset for counter tid
    int e1 = tot0 + s1 + add1 - v1;   // exclusive offset for counter tid+256
    // reserve global staging space per bucket (bcnt is NB_MAX ints, zeroed)
    resv[tid]       = v0 ? atomicAdd(&bcnt[tid], v0) : 0;
    resv[tid + 256] = v1 ? atomicAdd(&bcnt[tid + 256], v1) : 0;
    loc[tid] = e0; loc[tid + 256] = e1;
    __syncthreads();
    // pass 2: scatter records into LDS grouped by bucket
    for (int k = tid; k < cE; k += 256) {
        int s = src[base + k], d = dst[base + k];
        int b = d >> BSH;
        int p = atomicAdd(&loc[b], 1);
        sorted[p] = ((uint32_t)s << BSH) | (uint32_t)(d & ((1 << BSH) - 1));
    }
    __syncthreads();
    // flush: thread t flushes buckets t and t+256 as contiguous runs
#pragma unroll
    for (int half = 0; half < 2; ++half) {
        int b = tid + half * 256;
        int c = cnt[b];
        if (c > 0 && b < NB) {
            int st = loc[b] - c;          // loc was bumped to end by scatter
            int r = resv[b];
            int lim = SCAP - r;           // statistically impossible overflow guard
            int cw = min(c, max(lim, 0));
            size_t gb = (size_t)b * SCAP + r;
            for (int j = 0; j < cw; ++j) staging[gb + j] = sorted[st + j];
        }
    }
}

// ====== K3: per-bucket sort -> rowptr, inv, CSR srcs (coalesced out) ======
// srcs output is PRE-SHIFTED by 5 (dword offset of the 32-dword row).
// Wave-level shfl scans: 3 __syncthreads total on the scan paths (was ~24).
__global__ __launch_bounds__(256) void sort_kernel(const int* __restrict__ bcnt,
                                                   const uint32_t* __restrict__ staging,
                                                   int* __restrict__ rowptr,
                                                   float* __restrict__ inv,
                                                   uint32_t* __restrict__ srcs,
                                                   int n, int E, int NB) {
    __shared__ uint32_t raw[SCAP];
    __shared__ uint32_t sorted[SCAP];
    __shared__ int scnt[1 << BSH];
    __shared__ int soff[1 << BSH];
    __shared__ int lcur[1 << BSH];
    __shared__ int wred[4];
    __shared__ int wsum[4];
    int tid = threadIdx.x;
    int lane = tid & 63, wv = tid >> 6;
    int b = blockIdx.x;
    int base = b << BSH;
    int nd = min(1 << BSH, n - base);
    int cb = min(bcnt[b], SCAP);

    // bucket global base = prefix sum of bcnt[0..b): per-thread partials,
    // wave shfl-reduce (no barriers), cross-wave via LDS (1 barrier).
    int part = 0;
    for (int j = tid; j < b; j += 256) part += bcnt[j];
#pragma unroll
    for (int o = 1; o < 64; o <<= 1) part += __shfl_xor(part, o, 64);
    if (lane == 0) wred[wv] = part;
    // zero histogram before the same barrier
    scnt[tid] = 0;
    __syncthreads();
    int bbase = wred[0] + wred[1] + wred[2] + wred[3];

    // load records, histogram by local dst
    for (int k = tid; k < cb; k += 256) {
        uint32_t w = staging[(size_t)b * SCAP + k];
        raw[k] = w;
        atomicAdd(&scnt[w & ((1 << BSH) - 1)], 1);
    }
    __syncthreads();
    // exclusive scan of 256 counters: wave shfl inclusive scan + cross-wave offsets
    int v = scnt[tid];
    int sc = v;
#pragma unroll
    for (int o = 1; o < 64; o <<= 1) {
        int t = __shfl_up(sc, o, 64);
        if (lane >= o) sc += t;
    }
    if (lane == 63) wsum[wv] = sc;
    __syncthreads();
    int add = 0;
    if (wv > 0) add += wsum[0];
    if (wv > 1) add += wsum[1];
    if (wv > 2) add += wsum[2];
    int incl = sc + add;
    soff[tid] = incl - v;
    lcur[tid] = incl - v;
    if (tid < nd) {
        rowptr[base + tid] = bbase + soff[tid];
        inv[base + tid] = rsqrtf((float)v + 1.0f);
    }
    if (b == NB - 1 && tid == 0) rowptr[n] = E;
    __syncthreads();
    // place into sorted order
    for (int k = tid; k < cb; k += 256) {
        uint32_t w = raw[k];
        int p = atomicAdd(&lcur[w & ((1 << BSH) - 1)], 1);
        sorted[p] = w >> BSH;
    }
    __syncthreads();
    for (int k = tid; k < cb; k += 256) srcs[bbase + k] = sorted[k] << 5;  // coalesced, pre-shifted
}

// ====== MFMA GEMM: [n,64] @ [64,64] -> bf16 rows PRE-SCALED by inv[row]. ======
// R2-measured config: LDS-staged W, per-wave fragment build, 1024-block grid.
// 16x16x32 bf16, split-bf16 = fp32-exact.
template <int XBF>
__global__ __launch_bounds__(256) void gemm64_mfma(const void* __restrict__ Xv,
                                                   const float* __restrict__ W,
                                                   const float* __restrict__ inv,
                                                   uint16_t* __restrict__ Y, int n) {
    __shared__ float Ws[DD * DD];
    int tid = threadIdx.x;
    for (int i = tid; i < DD * DD; i += 256) Ws[i] = W[i];
    __syncthreads();
    int lane = tid & 63, quad = lane >> 4, l16 = lane & 15;

    Frag bhi[4][2], blo[4][2];
#pragma unroll
    for (int t = 0; t < 4; ++t)
#pragma unroll
        for (int c = 0; c < 2; ++c) {
            int col = t * 16 + l16;
            int kb = c * 32 + quad * 8;
#pragma unroll
            for (int i = 0; i < 4; ++i) {
                float w0 = Ws[(kb + 2 * i) * DD + col];
                float w1 = Ws[(kb + 2 * i + 1) * DD + col];
                uint32_t h0 = f2bf(w0), h1 = f2bf(w1);
                uint32_t l0 = f2bf(w0 - bf2f(h0)), l1 = f2bf(w1 - bf2f(h1));
                bhi[t][c].d[i] = h0 | (h1 << 16);
                blo[t][c].d[i] = l0 | (l1 << 16);
            }
        }

    int ngroups = (n + 15) >> 4;
    int nwaves = gridDim.x * 4;
    int wid = blockIdx.x * 4 + (tid >> 6);
    for (int g = wid; g < ngroups; g += nwaves) {
        int rb = g << 4;
        int row = min(rb + l16, n - 1);
        f32x4 acc[4];
#pragma unroll
        for (int t = 0; t < 4; ++t) acc[t] = (f32x4){0.f, 0.f, 0.f, 0.f};
#pragma unroll
        for (int c = 0; c < 2; ++c) {
            Frag ahi, alo;
            if constexpr (XBF == 0) {
                const float* xr = (const float*)Xv + (size_t)row * DD + c * 32 + quad * 8;
                float4 x0 = *(const float4*)xr;
                float4 x1 = *(const float4*)(xr + 4);
                float f[8] = {x0.x, x0.y, x0.z, x0.w, x1.x, x1.y, x1.z, x1.w};
#pragma unroll
                for (int i = 0; i < 4; ++i) {
                    uint32_t h0 = f2bf(f[2 * i]), h1 = f2bf(f[2 * i + 1]);
                    ahi.d[i] = h0 | (h1 << 16);
                    alo.d[i] = f2bf(f[2 * i] - bf2f(h0)) | (f2bf(f[2 * i + 1] - bf2f(h1)) << 16);
                }
            } else {
                const int4* xr = (const int4*)((const uint32_t*)Xv + (size_t)row * 32 + c * 16 + quad * 4);
                int4 a = *xr;
                ahi.d[0] = a.x; ahi.d[1] = a.y; ahi.d[2] = a.z; ahi.d[3] = a.w;
            }
#pragma unroll
            for (int t = 0; t < 4; ++t) {
                acc[t] = __builtin_amdgcn_mfma_f32_16x16x32_bf16(ahi.v, bhi[t][c].v, acc[t], 0, 0, 0);
                acc[t] = __builtin_amdgcn_mfma_f32_16x16x32_bf16(ahi.v, blo[t][c].v, acc[t], 0, 0, 0);
                if constexpr (XBF == 0)
                    acc[t] = __builtin_amdgcn_mfma_f32_16x16x32_bf16(alo.v, bhi[t][c].v, acc[t], 0, 0, 0);
            }
        }
#pragma unroll
        for (int r = 0; r < 4; ++r) {
            int ro = rb + quad * 4 + r;
            if (ro < n) {
                float sc = inv[ro];
#pragma unroll
                for (int t = 0; t < 4; ++t)
                    Y[(size_t)ro * DD + t * 16 + l16] = (uint16_t)f2bf(acc[t][r] * sc);
            }
        }
    }
}

// ====== fused aggregation: TWO nodes per wave (32 lanes each), 4 edge-streams/node ======
// R3-measured config (best: 48.0 us, VGPR 16): 3 rows + 4 srcs in flight per stream.
// Half h (lanes h*32..h*32+31) owns node 2w+h. Group g (8 lanes) owns edge stream
// jstart+g, +4, ...; lane m loads row dwords 4m..4m+3 (16 B). Rows pre-scaled by
// inv[src]; whole sum (incl. self row) scaled by inv[dst] once at the end.
template <int MODE>
__global__ __launch_bounds__(256) void agg_kernel(const int* __restrict__ rowptr,
                                                  const uint32_t* __restrict__ srcs,  // pre-shifted <<5
                                                  const float* __restrict__ inv,
                                                  const uint32_t* __restrict__ XWb,  // [n][32] dwords
                                                  const float* __restrict__ b,
                                                  void* __restrict__ OUTv, int n) {
    int gid = blockIdx.x * 256 + threadIdx.x;
    int w = gid >> 6, lane = gid & 63;
    if (w * 2 >= n) return;
    int h = lane >> 5, l = lane & 31;
    int i = w * 2 + h;
    bool act = i < n;
    int ic = act ? i : n - 1;
    int g = l >> 3, m = l & 7;

    float a[8];
#pragma unroll
    for (int k = 0; k < 8; ++k) a[k] = 0.f;
    if (g == 0) {  // self-loop: row ic is pre-scaled by inv[ic]; final *iv gives inv^2
        int4 d = *(const int4*)(XWb + (size_t)ic * 32 + 4 * m);
        a[0] = bf_lo((uint32_t)d.x); a[1] = bf_hi((uint32_t)d.x);
        a[2] = bf_lo((uint32_t)d.y); a[3] = bf_hi((uint32_t)d.y);
        a[4] = bf_lo((uint32_t)d.z); a[5] = bf_hi((uint32_t)d.z);
        a[6] = bf_lo((uint32_t)d.w); a[7] = bf_hi((uint32_t)d.w);
    }

    int jstart = rowptr[ic];
    int jend = act ? rowptr[ic + 1] : jstart;
    if (jstart < jend) {
        int last = jend - 1;
        int jq = jstart + g;  // this group's stream: jq, jq+4, ...
        uint32_t s0 = srcs[min(jq, last)];
        uint32_t s1 = srcs[min(jq + 4, last)];
        uint32_t s2 = srcs[min(jq + 8, last)];
        uint32_t s3 = srcs[min(jq + 12, last)];
        int4 d0 = *(const int4*)(XWb + s0 + 4 * m);
        int4 d1 = *(const int4*)(XWb + s1 + 4 * m);
        int4 d2 = *(const int4*)(XWb + s2 + 4 * m);
        for (int j = jq; j < jend; j += 4) {
            uint32_t s4 = srcs[min(j + 16, last)];            // src prefetch (4 ahead)
            int4 d3 = *(const int4*)(XWb + s3 + 4 * m);       // row prefetch (3 ahead)
            a[0] += bf_lo((uint32_t)d0.x); a[1] += bf_hi((uint32_t)d0.x);
            a[2] += bf_lo((uint32_t)d0.y); a[3] += bf_hi((uint32_t)d0.y);
            a[4] += bf_lo((uint32_t)d0.z); a[5] += bf_hi((uint32_t)d0.z);
            a[6] += bf_lo((uint32_t)d0.w); a[7] += bf_hi((uint32_t)d0.w);
            s3 = s4;
            d0 = d1; d1 = d2; d2 = d3;
        }
    }

    // combine 4 groups within each half: lanes {l^8, l^16} (all intra-half)
#pragma unroll
    for (int k = 0; k < 8; ++k) {
        a[k] += __shfl_xor(a[k], 8, 64);
        a[k] += __shfl_xor(a[k], 16, 64);
    }

    float iv = inv[ic];  // half-uniform
    float4 bb0 = *(const float4*)(b + 8 * m);
    float4 bb1 = *(const float4*)(b + 8 * m + 4);
    float f0 = fmaf(a[0], iv, bb0.x), f1 = fmaf(a[1], iv, bb0.y);
    float f2 = fmaf(a[2], iv, bb0.z), f3 = fmaf(a[3], iv, bb0.w);
    float f4 = fmaf(a[4], iv, bb1.x), f5 = fmaf(a[5], iv, bb1.y);
    float f6 = fmaf(a[6], iv, bb1.z), f7 = fmaf(a[7], iv, bb1.w);

    if (MODE == 0) {
        if (act && g == 0) {
            int4 d;
            d.x = (int)((f2bf(fmaxf(f1, 0.f)) << 16) | f2bf(fmaxf(f0, 0.f)));
            d.y = (int)((f2bf(fmaxf(f3, 0.f)) << 16) | f2bf(fmaxf(f2, 0.f)));
            d.z = (int)((f2bf(fmaxf(f5, 0.f)) << 16) | f2bf(fmaxf(f4, 0.f)));
            d.w = (int)((f2bf(fmaxf(f7, 0.f)) << 16) | f2bf(fmaxf(f6, 0.f)));
            *(int4*)((uint32_t*)OUTv + (size_t)i * 32 + 4 * m) = d;
        }
    } else {
        // cross-feature reduce over m (lanes l^4, l^2, l^1 — intra-half)
        float mx = fmaxf(fmaxf(fmaxf(f0, f1), fmaxf(f2, f3)),
                         fmaxf(fmaxf(f4, f5), fmaxf(f6, f7)));
#pragma unroll
        for (int o = 4; o > 0; o >>= 1) mx = fmaxf(mx, __shfl_xor(mx, o, 64));
        float e = __expf(f0 - mx) + __expf(f1 - mx) + __expf(f2 - mx) + __expf(f3 - mx)
                + __expf(f4 - mx) + __expf(f5 - mx) + __expf(f6 - mx) + __expf(f7 - mx);
#pragma unroll
        for (int o = 4; o > 0; o >>= 1) e += __shfl_xor(e, o, 64);
        float ls = __logf(e);
        if (act && g == 0) {
            float4 r0 = make_float4(f0 - mx - ls, f1 - mx - ls, f2 - mx - ls, f3 - mx - ls);
            float4 r1 = make_float4(f4 - mx - ls, f5 - mx - ls, f6 - mx - ls, f7 - mx - ls);
            *(float4*)((float*)OUTv + (size_t)i * DD + 8 * m) = r0;
            *(float4*)((float*)OUTv + (size_t)i * DD + 8 * m + 4) = r1;
        }
    }
}

extern "C" void kernel_launch(void* const* d_in, const int* in_sizes, int n_in,
                              void* d_out, int out_size, void* d_ws, size_t ws_size,
                              hipStream_t stream) {
    const float* x  = (const float*)d_in[0];
    const int*   ei = (const int*)d_in[1];
    const float* W1 = (const float*)d_in[2];
    const float* b1 = (const float*)d_in[3];
    const float* W2 = (const float*)d_in[4];
    const float* b2 = (const float*)d_in[5];
    float* out = (float*)d_out;

    const int n = in_sizes[0] / DD;
    const int E = in_sizes[1] / 2;
    const int* src = ei;
    const int* dst = ei + E;
    const int NB = (n + (1 << BSH) - 1) >> BSH;  // 391 for n=100k

    // workspace layout (int units)
    size_t off = 0;
    int* base = (int*)d_ws;
    int* bcnt = base + off; off += NB_MAX;
    uint32_t* staging = (uint32_t*)(base + off); off += (size_t)NB_MAX * SCAP;
    uint32_t* srcs = (uint32_t*)(base + off); off += E;
    int* rowptr = base + off; off += (size_t)n + 1;
    float* inv  = (float*)(base + off); off += n;
    uint32_t* XWb = (uint32_t*)(base + off); off += (size_t)n * 32;  // bf16 [n][64]
    uint32_t* hb  = (uint32_t*)(base + off); off += (size_t)n * 32;  // bf16 [n][64]

    hipMemsetAsync(bcnt, 0, NB_MAX * sizeof(int), stream);
    bin_kernel<<<(E + BIN_CH - 1) / BIN_CH, 256, 0, stream>>>(src, dst, bcnt, staging, E, NB);
    sort_kernel<<<NB, 256, 0, stream>>>(bcnt, staging, rowptr, inv, srcs, n, E, NB);

    // agg grid: two nodes per wave (4 waves/block)
    const int ablocks = (n + 7) / 8;

    // layer 1 (gemm pre-scales rows by inv[row]; needs sort_kernel's inv -> same stream, ordered)
    gemm64_mfma<0><<<1024, 256, 0, stream>>>(x, W1, inv, (uint16_t*)XWb, n);
    agg_kernel<0><<<ablocks, 256, 0, stream>>>(rowptr, srcs, inv, XWb, b1, hb, n);

    // layer 2
    gemm64_mfma<1><<<1024, 256, 0, stream>>>(hb, W2, inv, (uint16_t*)XWb, n);
    agg_kernel<1><<<ablocks, 256, 0, stream>>>(rowptr, srcs, inv, XWb, b2, out, n);
}